// Round 20
// baseline (127.139 us; speedup 1.0000x reference)
//
#include <hip/hip_runtime.h>
#include <math.h>

#define NN 512
#define BB 16
#define TOTAL (BB * NN * NN)   // 4,194,304 cells
#define EPS_F 1e-5f
#define DELTA_F 0.05f

#define TILE_H 128              // tile rows (16 threads x 8)
#define TILE_W 64               // tile cols (16 threads x 4)
#define PTY 8
#define PTX 4
#define GUARD 16384             // halo stray <= ~10.3 KB

// bf16 helpers (storage only; all math in f32)
__device__ __forceinline__ float bf16_ld(unsigned short h) {
    return __uint_as_float((unsigned)h << 16);
}
__device__ __forceinline__ unsigned short bf16_st(float f) {
    unsigned b = __float_as_uint(f);
    return (unsigned short)((b + 0x7FFFu + ((b >> 16) & 1u)) >> 16);  // RNE
}

// 16-lane DPP shifts: boundary lanes -> 0, annihilated by ring cf=0
__device__ __forceinline__ float dpp_shr1(float x) {
    int r = __builtin_amdgcn_update_dpp(0, __float_as_int(x), 0x111, 0xf, 0xf, true);
    return __int_as_float(r);
}
__device__ __forceinline__ float dpp_shl1(float x) {
    int r = __builtin_amdgcn_update_dpp(0, __float_as_int(x), 0x101, 0xf, 0xf, true);
    return __int_as_float(r);
}

// ---------------------------------------------------------------------------
// Init (8 cells/thread): u0(bf16) = dir ? bc : 0 ; packed mask (1 bit/cell,
// one full byte per thread -> no partial-byte races) ;
// pre(bf16) = w_outer * [geom<=0.5] * (x·w_back + b)
// ---------------------------------------------------------------------------
__global__ __launch_bounds__(256) void init_kernel(
    const float4* __restrict__ xm4,
    unsigned short* __restrict__ u,
    unsigned char* __restrict__ pkm,
    unsigned short* __restrict__ pre,
    const float* __restrict__ w_back,
    const float* __restrict__ b_back)
{
    int g = blockIdx.x * 256 + threadIdx.x;      // 0 .. TOTAL/8-1
    int idx = g * 8;
    int j0 = idx & (NN - 1);
    int i  = (idx >> 9) & (NN - 1);
    float w0 = w_back[0], w1 = w_back[1], bb0 = b_back[0];
    float xs = (float)i * (1.0f / 511.0f);
    float dx = fminf(xs, 1.0f - xs);
    bool iedge = (i == 0) | (i == NN - 1);

    unsigned uw[4] = {0u, 0u, 0u, 0u};
    unsigned pw[4] = {0u, 0u, 0u, 0u};
    unsigned mb = 0u;
#pragma unroll
    for (int c = 0; c < 8; ++c) {
        float4 xm = xm4[idx + c];
        int j = j0 + c;
        bool dir = iedge | (j == 0) | (j == NN - 1) | (xm.z > 0.5f);
        unsigned us = bf16_st(dir ? xm.w : 0.0f);
        uw[c >> 1] |= us << ((c & 1) * 16);
        mb |= (dir ? 0u : 1u) << c;

        float rr = xm.x * w0 + xm.y * w1 + bb0;
        float ys = (float)j * (1.0f / 511.0f);
        float dd = fminf(dx, fminf(ys, 1.0f - ys));
        float ww = fminf(fmaxf(dd * (1.0f / DELTA_F), 0.0f), 1.0f);
        if (xm.z > 0.5f) ww = 0.0f;
        unsigned ps = bf16_st(ww * rr);
        pw[c >> 1] |= ps << ((c & 1) * 16);
    }
    *(uint4*)(u + idx)   = make_uint4(uw[0], uw[1], uw[2], uw[3]);
    *(uint4*)(pre + idx) = make_uint4(pw[0], pw[1], pw[2], pw[3]);
    pkm[g] = (unsigned char)mb;
}

// ---------------------------------------------------------------------------
// Tall register-tile stencil, templated halo. 16x16 threads, each owns
// 8 rows x 4 cols of a 128x64 tile (center (128-2H)x(64-2H), halo H>=ITERS).
// HALO=8 (non-final): aligned fast path — uint2 u loads, single mask byte
// (nibble-aligned), uint2/float4 stores (proven R19 kernel).
// HALO=10 (final): alignment degrades (gx0 = 2 mod 4) — 2x dword u loads,
// two-byte mask combine, predicated float2 stores (proven R18 store path).
// Inner loop: raster order keeps u[r][c+1], u[r+1][c] OLD when (r,c)
// updates; DPP per-row under wave lockstep. Ring cells frozen (cf=0)
// annihilate garbage halo via fma; guarded OOB reads decode finite and
// cannot cross the frozen global-edge rows/cols. Overlapping tiles
// (min-clamped origins) write identical values.
// ---------------------------------------------------------------------------
template<int ITERS, int HALO, bool FINAL>
__global__ __launch_bounds__(256, 4) void stencil_kernel(
    const unsigned short* __restrict__ uin,
    unsigned short* __restrict__ uout,      // bf16 dest (non-final)
    float* __restrict__ fout,               // f32 dest (final)
    const unsigned char* __restrict__ pkm,  // packed fluid mask, 1 bit/cell
    const unsigned short* __restrict__ pre,
    const float* __restrict__ logit,
    const float* __restrict__ y_mean,
    const float* __restrict__ y_std)
{
    constexpr int OUT_H = TILE_H - 2 * HALO;
    constexpr int OUT_W = TILE_W - 2 * HALO;

    __shared__ float xup[2][PTX][256];   // each thread's row 0 (for tr-1)
    __shared__ float xdn[2][PTX][256];   // each thread's row 7 (for tr+1)

    const int b   = blockIdx.z;
    const int oy  = min((int)blockIdx.y * OUT_H, NN - OUT_H);
    const int ox  = min((int)blockIdx.x * OUT_W, NN - OUT_W);
    const int tid = threadIdx.x;
    const int tr  = tid >> 4;
    const int tc  = tid & 15;
    const int R0  = tr * PTY;
    const int C0  = tc * PTX;
    const int ty0 = oy - HALO;
    const int tx0 = ox - HALO;

    const int slab = b * NN * NN;
    const unsigned short* ub = uin + slab;
    const unsigned char*  cb = pkm + b * (NN * NN / 8);

    const int gx0  = tx0 + C0;
    const int mcol = gx0 >> 3;
    const int msh  = gx0 & 7;

    float u[PTY][PTX];
    float cf[PTY][PTX];   // 1.0 = fluid (update), 0.0 = Dirichlet/frozen

    // ---- setup (guarded offsets; tile ring frozen) ----
#pragma unroll
    for (int r = 0; r < PTY; ++r) {
        int ty = R0 + r;
        int gy = ty0 + ty;
        int off = gy * NN + gx0;
        unsigned uwv[2];
        unsigned mbits;
        if constexpr (HALO == 8) {
            uint2 v = *(const uint2*)(ub + off);      // 8B-aligned (gx0%4==0)
            uwv[0] = v.x; uwv[1] = v.y;
            mbits = cb[gy * (NN / 8) + mcol];         // msh in {0,4}
        } else {
            uwv[0] = *(const unsigned*)(ub + off);        // 4B-aligned (gx0 even)
            uwv[1] = *(const unsigned*)(ub + off + 2);
            unsigned b0 = cb[gy * (NN / 8) + mcol];
            unsigned b1 = cb[gy * (NN / 8) + mcol + 1];
            mbits = b0 | (b1 << 8);                   // msh in {2,6}: spans bytes
        }
#pragma unroll
        for (int c = 0; c < PTX; ++c) {
            unsigned hw = (uwv[c >> 1] >> ((c & 1) * 16)) & 0xFFFFu;
            u[r][c] = __uint_as_float(hw << 16);
            unsigned m = (mbits >> (msh + c)) & 1u;
            int tx = C0 + c;
            bool ring = (ty == 0) | (ty == TILE_H - 1) | (tx == 0) | (tx == TILE_W - 1);
            cf[r][c] = (ring || m == 0u) ? 0.0f : 1.0f;
        }
    }

    const int tup = (tid >= 16)  ? tid - 16 : tid;   // clamped; garbage killed by ring
    const int tdn = (tid < 240)  ? tid + 16 : tid;

    // ---- ITERS fused Jacobi iterations, all in registers ----
#pragma unroll 1
    for (int t = 0; t < ITERS; ++t) {
        const int pb = t & 1;
#pragma unroll
        for (int w = 0; w < PTX; ++w) {
            xup[pb][w][tid] = u[0][w];
            xdn[pb][w][tid] = u[PTY - 1][w];
        }
        __syncthreads();
        float th[PTX], bh[PTX];
#pragma unroll
        for (int w = 0; w < PTX; ++w) {
            th[w] = xdn[pb][w][tup];   // garbage for tr==0: ring cf=0 kills it
            bh[w] = xup[pb][w][tdn];   // garbage for tr==15: ring cf=0 kills it
        }
        float prow[PTX];               // OLD values of row r-1
#pragma unroll
        for (int c = 0; c < PTX; ++c) prow[c] = th[c];
#pragma unroll
        for (int r = 0; r < PTY; ++r) {
            float lshr = dpp_shr1(u[r][PTX - 1]);
            float rshr = dpp_shl1(u[r][0]);
            float prevold = lshr;
#pragma unroll
            for (int c = 0; c < PTX; ++c) {
                float od = u[r][c];
                float up = prow[c];
                float dn = (r < PTY - 1) ? u[r + 1][c] : bh[c];   // still old
                float lf = prevold;
                float rt = (c < PTX - 1) ? u[r][c + 1] : rshr;    // still old
                float s  = (up + dn) + (lf + rt);
                float tq = __builtin_fmaf(0.25f, s, -od);
                u[r][c]  = __builtin_fmaf(cf[r][c], tq, od);
                prevold  = od;
                prow[c]  = od;
            }
        }
    }

    // ---- store valid center ----
    if constexpr (!FINAL) {
        // HALO==8: inner threads tr in [1,15), tc in [2,14); aligned uint2
        const bool inner = (tr >= 1) & (tr < 15) & (tc >= 2) & (tc < 14);
        if (inner) {
            unsigned short* og = uout + slab;
            int gcol = ox + C0 - HALO;
#pragma unroll
            for (int r = 0; r < PTY; ++r) {
                int grow = oy + R0 + r - HALO;
                unsigned a = (unsigned)bf16_st(u[r][0]) | ((unsigned)bf16_st(u[r][1]) << 16);
                unsigned d = (unsigned)bf16_st(u[r][2]) | ((unsigned)bf16_st(u[r][3]) << 16);
                *(uint2*)(og + grow * NN + gcol) = make_uint2(a, d);
            }
        }
    } else {
        // HALO==10: predicated epilogue store (gcol = 2 mod 4 -> float2 pairs)
        float* og = fout + slab;
        const unsigned short* pg = pre + slab;
        float rs  = 0.25f / (1.0f + expf(-logit[0]));
        float ym  = y_mean[0];
        float inv = 1.0f / (y_std[0] + EPS_F);
        const bool colfull = (C0 >= HALO + 2) & (C0 + PTX <= HALO + OUT_W);
#pragma unroll
        for (int r = 0; r < PTY; ++r) {
            int cy = R0 + r - HALO;
            if ((unsigned)cy >= (unsigned)OUT_H) continue;
            int grow = oy + cy;
            if (colfull) {
                int gcol = ox + C0 - HALO;   // even
                unsigned p0 = *(const unsigned*)(pg + grow * NN + gcol);
                unsigned p1 = *(const unsigned*)(pg + grow * NN + gcol + 2);
                float pr0 = bf16_ld((unsigned short)(p0 & 0xFFFFu));
                float pr1 = bf16_ld((unsigned short)(p0 >> 16));
                float pr2 = bf16_ld((unsigned short)(p1 & 0xFFFFu));
                float pr3 = bf16_ld((unsigned short)(p1 >> 16));
                float2 o1, o2;
                o1.x = __builtin_fmaf(rs, pr0, (u[r][0] - ym) * inv);
                o1.y = __builtin_fmaf(rs, pr1, (u[r][1] - ym) * inv);
                o2.x = __builtin_fmaf(rs, pr2, (u[r][2] - ym) * inv);
                o2.y = __builtin_fmaf(rs, pr3, (u[r][3] - ym) * inv);
                *(float2*)(og + grow * NN + gcol)     = o1;   // 8B-aligned
                *(float2*)(og + grow * NN + gcol + 2) = o2;
            } else {
#pragma unroll
                for (int c = 0; c < PTX; ++c) {
                    int cx = C0 + c - HALO;
                    if ((unsigned)cx < (unsigned)OUT_W) {
                        int gj = ox + cx;
                        float e = (u[r][c] - ym) * inv;
                        float p = bf16_ld(pg[grow * NN + gj]);
                        og[grow * NN + gj] = __builtin_fmaf(rs, p, e);
                    }
                }
            }
        }
    }
}

// ---------------------------------------------------------------------------
extern "C" void kernel_launch(void* const* d_in, const int* in_sizes, int n_in,
                              void* d_out, int out_size, void* d_ws, size_t ws_size,
                              hipStream_t stream)
{
    const float* x_mix  = (const float*)d_in[0];
    const float* w_back = (const float*)d_in[1];
    const float* b_back = (const float*)d_in[2];
    const float* logit  = (const float*)d_in[3];
    const float* y_mean = (const float*)d_in[4];
    const float* y_std  = (const float*)d_in[5];

    float* out = (float*)d_out;

    // Workspace: [GUARD][u_a 2T][u_b 2T][pre 2T][pkm T/8][~2KB slack]
    // u halo reads stray <= ~10.3 KB past either end of u_a/u_b -> land in
    // an adjacent defined region or the guard (finite bf16 patterns). Mask
    // reads stray <= ~1.5 KB past pkm bounds -> pre region / workspace tail;
    // mask garbage only affects cells behind the frozen global edge (cannot
    // propagate through the 5-point stencil). pre reads and all stores are
    // strictly in-range.
    char* ws = (char*)d_ws;
    unsigned short* u_a = (unsigned short*)(ws + GUARD);
    unsigned short* u_b = (unsigned short*)(ws + GUARD + (size_t)TOTAL * 2);
    unsigned short* pre = (unsigned short*)(ws + GUARD + (size_t)TOTAL * 4);
    unsigned char*  pkm = (unsigned char*) (ws + GUARD + (size_t)TOTAL * 6);

    init_kernel<<<TOTAL / 8 / 256, 256, 0, stream>>>(
        (const float4*)x_mix, u_a, pkm, pre, w_back, b_back);

    // 50 iters = 5 launches x 8 (halo 8) + 1 FINAL launch x 10 (halo 10,
    // fused epilogue). Chain: a->b, b->a, a->b, b->a, a->b, then b->out.
    dim3 g8((NN + 48 - 1) / 48, (NN + 112 - 1) / 112, BB);    // 11 x 5 x 16
    dim3 g10((NN + 44 - 1) / 44, (NN + 108 - 1) / 108, BB);   // 12 x 5 x 16
    stencil_kernel<8, 8, false><<<g8, 256, 0, stream>>>(u_a, u_b, out, pkm,
        pre, logit, y_mean, y_std);
    stencil_kernel<8, 8, false><<<g8, 256, 0, stream>>>(u_b, u_a, out, pkm,
        pre, logit, y_mean, y_std);
    stencil_kernel<8, 8, false><<<g8, 256, 0, stream>>>(u_a, u_b, out, pkm,
        pre, logit, y_mean, y_std);
    stencil_kernel<8, 8, false><<<g8, 256, 0, stream>>>(u_b, u_a, out, pkm,
        pre, logit, y_mean, y_std);
    stencil_kernel<8, 8, false><<<g8, 256, 0, stream>>>(u_a, u_b, out, pkm,
        pre, logit, y_mean, y_std);
    stencil_kernel<10, 10, true><<<g10, 256, 0, stream>>>(u_b, u_a, out, pkm,
        pre, logit, y_mean, y_std);
}

// Round 21
// 124.511 us; speedup vs baseline: 1.0211x; 1.0211x over previous
//
#include <hip/hip_runtime.h>
#include <math.h>

#define NN 512
#define BB 16
#define TOTAL (BB * NN * NN)   // 4,194,304 cells
#define EPS_F 1e-5f
#define DELTA_F 0.05f

#define HALO 8
#define TILE_H 128              // tile rows (16 threads x 8)
#define TILE_W 64               // tile cols (16 threads x 4)
#define OUT_H  112              // valid center rows
#define OUT_W  48               // valid center cols
#define PTY 8
#define PTX 4
#define GUARD 16384             // halo stray <= ~8.3 KB

// bf16 helpers (storage only; all math in f32)
__device__ __forceinline__ float bf16_ld(unsigned short h) {
    return __uint_as_float((unsigned)h << 16);
}
__device__ __forceinline__ unsigned short bf16_st(float f) {
    unsigned b = __float_as_uint(f);
    return (unsigned short)((b + 0x7FFFu + ((b >> 16) & 1u)) >> 16);  // RNE
}

// 16-lane DPP shifts: boundary lanes -> 0, annihilated by ring cf=0
__device__ __forceinline__ float dpp_shr1(float x) {
    int r = __builtin_amdgcn_update_dpp(0, __float_as_int(x), 0x111, 0xf, 0xf, true);
    return __int_as_float(r);
}
__device__ __forceinline__ float dpp_shl1(float x) {
    int r = __builtin_amdgcn_update_dpp(0, __float_as_int(x), 0x101, 0xf, 0xf, true);
    return __int_as_float(r);
}

// ---------------------------------------------------------------------------
// Init (8 cells/thread): u0(bf16) = dir ? bc : 0 ; packed mask (1 bit/cell,
// one full byte per thread -> no partial-byte races) ;
// pre(bf16) = w_outer * [geom<=0.5] * (x·w_back + b)
// ---------------------------------------------------------------------------
__global__ __launch_bounds__(256) void init_kernel(
    const float4* __restrict__ xm4,
    unsigned short* __restrict__ u,
    unsigned char* __restrict__ pkm,
    unsigned short* __restrict__ pre,
    const float* __restrict__ w_back,
    const float* __restrict__ b_back)
{
    int g = blockIdx.x * 256 + threadIdx.x;      // 0 .. TOTAL/8-1
    int idx = g * 8;
    int j0 = idx & (NN - 1);
    int i  = (idx >> 9) & (NN - 1);
    float w0 = w_back[0], w1 = w_back[1], bb0 = b_back[0];
    float xs = (float)i * (1.0f / 511.0f);
    float dx = fminf(xs, 1.0f - xs);
    bool iedge = (i == 0) | (i == NN - 1);

    unsigned uw[4] = {0u, 0u, 0u, 0u};
    unsigned pw[4] = {0u, 0u, 0u, 0u};
    unsigned mb = 0u;
#pragma unroll
    for (int c = 0; c < 8; ++c) {
        float4 xm = xm4[idx + c];
        int j = j0 + c;
        bool dir = iedge | (j == 0) | (j == NN - 1) | (xm.z > 0.5f);
        unsigned us = bf16_st(dir ? xm.w : 0.0f);
        uw[c >> 1] |= us << ((c & 1) * 16);
        mb |= (dir ? 0u : 1u) << c;

        float rr = xm.x * w0 + xm.y * w1 + bb0;
        float ys = (float)j * (1.0f / 511.0f);
        float dd = fminf(dx, fminf(ys, 1.0f - ys));
        float ww = fminf(fmaxf(dd * (1.0f / DELTA_F), 0.0f), 1.0f);
        if (xm.z > 0.5f) ww = 0.0f;
        unsigned ps = bf16_st(ww * rr);
        pw[c >> 1] |= ps << ((c & 1) * 16);
    }
    *(uint4*)(u + idx)   = make_uint4(uw[0], uw[1], uw[2], uw[3]);
    *(uint4*)(pre + idx) = make_uint4(pw[0], pw[1], pw[2], pw[3]);
    pkm[g] = (unsigned char)mb;
}

// ---------------------------------------------------------------------------
// Tall register-tile stencil (R17 geometry) + bit-packed mask + lean loop.
// 16x16 threads, each owns 8 rows x 4 cols of a 128x64 tile (112x48 center,
// halo 8 >= ITERS). Mask: 1 byte load per row per thread (nibble-aligned),
// 8x fewer mask bytes than u8. Inner loop: raster order means u[r][c+1] and
// u[r+1][c] still hold OLD values when cell (r,c) updates, so only the left
// neighbor needs a saved scalar; DPP lsh/rsh computed per-row (wave lockstep
// keeps them reading old values). Ring cells frozen (cf=0) annihilate
// garbage halo values via fma; guarded OOB reads decode finite and cannot
// cross the frozen global-edge rows/cols. Overlapping tiles (min-clamped
// origins) write identical values.
// ---------------------------------------------------------------------------
template<int ITERS, bool FINAL>
__global__ __launch_bounds__(256, 4) void stencil_kernel(
    const unsigned short* __restrict__ uin,
    unsigned short* __restrict__ uout,      // bf16 dest (non-final)
    float* __restrict__ fout,               // f32 dest (final)
    const unsigned char* __restrict__ pkm,  // packed fluid mask, 1 bit/cell
    const unsigned short* __restrict__ pre,
    const float* __restrict__ logit,
    const float* __restrict__ y_mean,
    const float* __restrict__ y_std)
{
    __shared__ float xup[2][PTX][256];   // each thread's row 0 (for tr-1)
    __shared__ float xdn[2][PTX][256];   // each thread's row 7 (for tr+1)

    const int b   = blockIdx.z;
    const int oy  = min((int)blockIdx.y * OUT_H, NN - OUT_H);
    const int ox  = min((int)blockIdx.x * OUT_W, NN - OUT_W);
    const int tid = threadIdx.x;
    const int tr  = tid >> 4;          // 0..15, owns 8 rows
    const int tc  = tid & 15;          // 0..15, owns 4 cols
    const int R0  = tr * PTY;
    const int C0  = tc * PTX;
    const int ty0 = oy - HALO;
    const int tx0 = ox - HALO;

    const int slab = b * NN * NN;
    const unsigned short* ub = uin + slab;
    const unsigned char*  cb = pkm + b * (NN * NN / 8);

    const int gx0  = tx0 + C0;         // global col of this thread's col 0
    const int mcol = gx0 >> 3;         // mask byte column (arith shift ok)
    const int msh  = gx0 & 7;          // 0 or 4 (nibble-aligned)

    float u[PTY][PTX];
    float cf[PTY][PTX];   // 1.0 = fluid (update), 0.0 = Dirichlet/frozen

    // ---- setup: per row one uint2(u16x4) + one mask byte, guarded ----
#pragma unroll
    for (int r = 0; r < PTY; ++r) {
        int ty = R0 + r;
        int gy = ty0 + ty;
        int off = gy * NN + gx0;                  // may stray into guard: finite
        uint2 v = *(const uint2*)(ub + off);
        unsigned mbyte = cb[gy * (NN / 8) + mcol];
        unsigned uwv[2] = {v.x, v.y};
#pragma unroll
        for (int c = 0; c < PTX; ++c) {
            unsigned hw = (uwv[c >> 1] >> ((c & 1) * 16)) & 0xFFFFu;
            u[r][c] = __uint_as_float(hw << 16);
            unsigned m = (mbyte >> (msh + c)) & 1u;
            int tx = C0 + c;
            bool ring = (ty == 0) | (ty == TILE_H - 1) | (tx == 0) | (tx == TILE_W - 1);
            cf[r][c] = (ring || m == 0u) ? 0.0f : 1.0f;
        }
    }

    const int tup = (tid >= 16)  ? tid - 16 : tid;   // clamped; garbage killed by ring
    const int tdn = (tid < 240)  ? tid + 16 : tid;

    // ---- ITERS fused Jacobi iterations, all in registers ----
#pragma unroll 1
    for (int t = 0; t < ITERS; ++t) {
        const int pb = t & 1;
#pragma unroll
        for (int w = 0; w < PTX; ++w) {
            xup[pb][w][tid] = u[0][w];
            xdn[pb][w][tid] = u[PTY - 1][w];
        }
        __syncthreads();
        float th[PTX], bh[PTX];
#pragma unroll
        for (int w = 0; w < PTX; ++w) {
            th[w] = xdn[pb][w][tup];   // garbage for tr==0: ring cf=0 kills it
            bh[w] = xup[pb][w][tdn];   // garbage for tr==15: ring cf=0 kills it
        }
        float prow[PTX];               // OLD values of row r-1
#pragma unroll
        for (int c = 0; c < PTX; ++c) prow[c] = th[c];
#pragma unroll
        for (int r = 0; r < PTY; ++r) {
            // DPP on old row r (lockstep: neighbors haven't touched row r yet)
            float lshr = dpp_shr1(u[r][PTX - 1]);
            float rshr = dpp_shl1(u[r][0]);
            float prevold = lshr;
#pragma unroll
            for (int c = 0; c < PTX; ++c) {
                float od = u[r][c];
                float up = prow[c];
                float dn = (r < PTY - 1) ? u[r + 1][c] : bh[c];   // still old
                float lf = prevold;
                float rt = (c < PTX - 1) ? u[r][c + 1] : rshr;    // still old
                float s  = (up + dn) + (lf + rt);
                float tq = __builtin_fmaf(0.25f, s, -od);
                u[r][c]  = __builtin_fmaf(cf[r][c], tq, od);
                prevold  = od;
                prow[c]  = od;
            }
        }
    }

    // ---- store center 112x48: threads tr in [1,15), tc in [2,14) ----
    const bool inner = (tr >= 1) & (tr < 15) & (tc >= 2) & (tc < 14);
    if (!FINAL) {
        if (inner) {
            unsigned short* og = uout + slab;
            int gcol = ox + C0 - HALO;
#pragma unroll
            for (int r = 0; r < PTY; ++r) {
                int grow = oy + R0 + r - HALO;
                unsigned a = (unsigned)bf16_st(u[r][0]) | ((unsigned)bf16_st(u[r][1]) << 16);
                unsigned d = (unsigned)bf16_st(u[r][2]) | ((unsigned)bf16_st(u[r][3]) << 16);
                *(uint2*)(og + grow * NN + gcol) = make_uint2(a, d);
            }
        }
    } else {
        if (inner) {
            float* og = fout + slab;
            const unsigned short* pg = pre + slab;
            float rs  = 0.25f / (1.0f + expf(-logit[0]));
            float ym  = y_mean[0];
            float inv = 1.0f / (y_std[0] + EPS_F);
            int gcol = ox + C0 - HALO;
#pragma unroll
            for (int r = 0; r < PTY; ++r) {
                int grow = oy + R0 + r - HALO;
                uint2 pv = *(const uint2*)(pg + grow * NN + gcol);
                unsigned pwv[2] = {pv.x, pv.y};
                float4 o;
                float* op = &o.x;
#pragma unroll
                for (int c = 0; c < PTX; ++c) {
                    float e = (u[r][c] - ym) * inv;
                    float p = bf16_ld((unsigned short)((pwv[c >> 1] >> ((c & 1) * 16)) & 0xFFFFu));
                    op[c] = __builtin_fmaf(rs, p, e);
                }
                *(float4*)(og + grow * NN + gcol) = o;
            }
        }
    }
}

// ---------------------------------------------------------------------------
extern "C" void kernel_launch(void* const* d_in, const int* in_sizes, int n_in,
                              void* d_out, int out_size, void* d_ws, size_t ws_size,
                              hipStream_t stream)
{
    const float* x_mix  = (const float*)d_in[0];
    const float* w_back = (const float*)d_in[1];
    const float* b_back = (const float*)d_in[2];
    const float* logit  = (const float*)d_in[3];
    const float* y_mean = (const float*)d_in[4];
    const float* y_std  = (const float*)d_in[5];

    float* out = (float*)d_out;

    // Workspace: [GUARD][u_a 2T][u_b 2T][pre 2T][pkm T/8][GUARD]
    // u halo reads stray <= ~8.3 KB past either end of u_a/u_b -> land in an
    // adjacent defined region or a guard (finite bf16 patterns). Mask reads
    // stray <= ~600 B -> pre region / tail guard; mask garbage only affects
    // cells behind the frozen global edge (cannot propagate). pre reads and
    // all stores are strictly in-range.
    char* ws = (char*)d_ws;
    unsigned short* u_a = (unsigned short*)(ws + GUARD);
    unsigned short* u_b = (unsigned short*)(ws + GUARD + (size_t)TOTAL * 2);
    unsigned short* pre = (unsigned short*)(ws + GUARD + (size_t)TOTAL * 4);
    unsigned char*  pkm = (unsigned char*) (ws + GUARD + (size_t)TOTAL * 6);

    init_kernel<<<TOTAL / 8 / 256, 256, 0, stream>>>(
        (const float4*)x_mix, u_a, pkm, pre, w_back, b_back);

    // 50 iters = 6 launches x 8 + 1 launch x 2 (fused epilogue).
    // Chain: a->b, b->a, a->b, b->a, a->b, b->a, then FINAL a->out.
    dim3 sgrid((NN + OUT_W - 1) / OUT_W, (NN + OUT_H - 1) / OUT_H, BB);  // 11x5x16
    stencil_kernel<8, false><<<sgrid, 256, 0, stream>>>(u_a, u_b, out, pkm,
        pre, logit, y_mean, y_std);
    stencil_kernel<8, false><<<sgrid, 256, 0, stream>>>(u_b, u_a, out, pkm,
        pre, logit, y_mean, y_std);
    stencil_kernel<8, false><<<sgrid, 256, 0, stream>>>(u_a, u_b, out, pkm,
        pre, logit, y_mean, y_std);
    stencil_kernel<8, false><<<sgrid, 256, 0, stream>>>(u_b, u_a, out, pkm,
        pre, logit, y_mean, y_std);
    stencil_kernel<8, false><<<sgrid, 256, 0, stream>>>(u_a, u_b, out, pkm,
        pre, logit, y_mean, y_std);
    stencil_kernel<8, false><<<sgrid, 256, 0, stream>>>(u_b, u_a, out, pkm,
        pre, logit, y_mean, y_std);
    stencil_kernel<2, true><<<sgrid, 256, 0, stream>>>(u_a, u_b, out, pkm,
        pre, logit, y_mean, y_std);
}